// Round 10
// baseline (112.929 us; speedup 1.0000x reference)
//
#include <hip/hip_runtime.h>
#include <math.h>

#define CIN   3
#define COUT  16
#define DHW   64
#define NCP   8                       // co-pairs
#define GP    56                      // floats per (c,copair) LDS group: 27 v2f + pad

typedef float v2f __attribute__((ext_vector_type(2)));

// Real packed fp32 FMA over a co-pair, splatting x from lo/hi half of an
// ALIGNED v2f via op_sel (no pair-building movs). XLO proven on HW in R9.
//   XLO: lo: w.lo*x.lo+acc.lo ; hi: w.hi*x.lo+acc.hi
#define PK_FMA_XLO(acc, w2, x2) \
    asm("v_pk_fma_f32 %0, %1, %2, %0 op_sel_hi:[1,0,1]" : "+v"(acc) : "v"(w2), "v"(x2))
//   XHI: lo: w.lo*x.hi+acc.lo ; hi: w.hi*x.hi+acc.hi
#define PK_FMA_XHI(acc, w2, x2) \
    asm("v_pk_fma_f32 %0, %1, %2, %0 op_sel:[0,1,0] op_sel_hi:[1,1,1]" : "+v"(acc) : "v"(w2), "v"(x2))

// One thread per FOUR output voxels (n,d,h,w0..w0+3).
// R10: V=4 (T_LDS = 102/V us -> 27us weight-broadcast floor) + real pk FMA
// over co-pairs (648 pk/voxel, T_VALU ~11us). pooled[4][16] parks in LDS
// (R8-proven same-thread RAW needs no barrier) to make registers fit.
// R1-R9 model: dur = max(T_LDS, T_VALU_with_bloat); R5/R9 (V=2) sat at the
// 54us LDS floor, R6 (V=4, fake pk) at ~2.5x VALU bloat.
//
// ConvTranspose3d(k=3,s=2,p=1,op=1)+MaxPool3d(2): od=2*id-1+kd =>
// kd==1 -> even pool pos, id=d ; kd==0 -> odd, id=d+1 ; kd==2 -> odd, id=d.
// Same in h,w. Each of 27 taps hits exactly one of 8 pool positions.
__global__ __launch_bounds__(128, 2) void fused_convt_pool_softmax_swish_max(
    const float* __restrict__ x,      // [N,CIN,64,64,64]
    const float* __restrict__ w,      // [CIN,COUT,3,3,3]
    const float* __restrict__ bias,   // [COUT]
    const float* __restrict__ sub,    // [COUT]
    float* __restrict__ out)          // [N,64,64,64]
{
    __shared__ float  wsm[CIN * NCP * GP];           // 24*56*4 = 5376 B
    __shared__ float4 plds[NCP][2][128];             // 32768 B  (total 38144)

    const int tid = threadIdx.y * 16 + threadIdx.x;
    // Stage weights pre-paired: group (c,cp) holds v2f pairs
    //   slot 2t+lane = w[c][2cp+lane][t],  t=0..26
    for (int i = tid; i < CIN * COUT * 27; i += 128) {
        const int c   = i / (COUT * 27);
        const int rem = i - c * COUT * 27;
        const int co  = rem / 27;
        const int t   = rem - co * 27;
        wsm[(c * NCP + (co >> 1)) * GP + 2 * t + (co & 1)] = w[i];
    }
    __syncthreads();

    const int tx = threadIdx.x;                      // w-quad index, 0..15
    const int h  = blockIdx.x * 8 + threadIdx.y;
    const int d  = blockIdx.y;
    const int n  = blockIdx.z;
    const int w0 = tx * 4;                           // outputs w0..w0+3; inputs w0..w0+4

    // X[c][dd][hh][pe] = aligned v2f pairs {x[w0+2pe], x[w0+2pe+1]}, pe=0..2
    // (element w0+4 sits in pair 2 lo; pair 2 hi unused=0)
    v2f X[CIN][2][2][3];
    const size_t nbase = (size_t)n * CIN * DHW * DHW * DHW;
    const bool w4ok = (w0 + 4 < DHW);
    const int  off4 = w4ok ? 4 : 0;                  // clamped, stays in-bounds
#pragma unroll
    for (int c = 0; c < CIN; ++c) {
#pragma unroll
        for (int dd = 0; dd < 2; ++dd) {
#pragma unroll
            for (int hh = 0; hh < 2; ++hh) {
                const int id = d + dd;
                const int ih = h + hh;
                float4 q = make_float4(0.f, 0.f, 0.f, 0.f);
                float x4 = 0.0f;
                if (id < DHW && ih < DHW) {
                    const float* row = x + nbase + (((size_t)c * DHW + id) * DHW + ih) * DHW + w0;
                    q = *(const float4*)row;                  // 16B-aligned
                    const float t = row[off4];
                    x4 = w4ok ? t : 0.0f;
                }
                v2f p0; p0.x = q.x; p0.y = q.y;
                v2f p1; p1.x = q.z; p1.y = q.w;
                v2f p2; p2.x = x4;  p2.y = 0.0f;
                X[c][dd][hh][0] = p0;
                X[c][dd][hh][1] = p1;
                X[c][dd][hh][2] = p2;
            }
        }
    }

#pragma unroll
    for (int cp = 0; cp < NCP; ++cp) {
        v2f acc[4][2][2][2];                         // [vox][pd][ph][pw], v2f over co-pair
#pragma unroll
        for (int i = 0; i < 32; ++i) { v2f z; z.x = 0.f; z.y = 0.f; (&acc[0][0][0][0])[i] = z; }
#pragma unroll
        for (int c = 0; c < CIN; ++c) {
            const float4* wq4 = (const float4*)&wsm[(c * NCP + cp) * GP];
            float4 qw[14];
#pragma unroll
            for (int t = 0; t < 14; ++t) qw[t] = wq4[t];     // 14x ds_read_b128 broadcast
            const v2f* wp = (const v2f*)&qw[0];              // wp[t] = {w_co, w_co+1}, t=0..26
#pragma unroll
            for (int kd = 0; kd < 3; ++kd) {
                const int pd = (kd == 1) ? 0 : 1;
                const int dd = (kd == 0) ? 1 : 0;
#pragma unroll
                for (int kh = 0; kh < 3; ++kh) {
                    const int ph = (kh == 1) ? 0 : 1;
                    const int hh = (kh == 0) ? 1 : 0;
#pragma unroll
                    for (int kw = 0; kw < 3; ++kw) {
                        const int pw = (kw == 1) ? 0 : 1;
                        const int ww = (kw == 0) ? 1 : 0;
                        const int t  = kd * 9 + kh * 3 + kw;
#pragma unroll
                        for (int v = 0; v < 4; ++v) {        // output voxel w0+v
                            const int e  = v + ww;           // x element 0..4
                            const int pe = e >> 1;
                            if ((e & 1) == 0) {
                                PK_FMA_XLO(acc[v][pd][ph][pw], wp[t], X[c][dd][hh][pe]);
                            } else {
                                PK_FMA_XHI(acc[v][pd][ph][pw], wp[t], X[c][dd][hh][pe]);
                            }
                        }
                    }
                }
            }
        }
        // pool (max over 8 positions; bias after max == before, uniform shift)
        v2f bp; bp.x = bias[2 * cp]; bp.y = bias[2 * cp + 1];
        v2f mm[4];
#pragma unroll
        for (int v = 0; v < 4; ++v) {
            const v2f* a = &acc[v][0][0][0];
            v2f m0 = __builtin_elementwise_max(__builtin_elementwise_max(a[0], a[1]),
                                               __builtin_elementwise_max(a[2], a[3]));
            v2f m1 = __builtin_elementwise_max(__builtin_elementwise_max(a[4], a[5]),
                                               __builtin_elementwise_max(a[6], a[7]));
            mm[v] = __builtin_elementwise_max(m0, m1) + bp;
        }
        float4 p01; p01.x = mm[0].x; p01.y = mm[0].y; p01.z = mm[1].x; p01.w = mm[1].y;
        float4 p23; p23.x = mm[2].x; p23.y = mm[2].y; p23.z = mm[3].x; p23.w = mm[3].y;
        plds[cp][0][tid] = p01;                      // ds_write_b128
        plds[cp][1][tid] = p23;
    }

    // ---- epilogue: same-thread LDS RAW (ordered by lgkmcnt, no barrier) ----
    float pooled[4][COUT];
#pragma unroll
    for (int cp = 0; cp < NCP; ++cp) {
        const float4 qa = plds[cp][0][tid];
        const float4 qb = plds[cp][1][tid];
        pooled[0][2 * cp] = qa.x; pooled[0][2 * cp + 1] = qa.y;
        pooled[1][2 * cp] = qa.z; pooled[1][2 * cp + 1] = qa.w;
        pooled[2][2 * cp] = qb.x; pooled[2][2 * cp + 1] = qb.y;
        pooled[3][2 * cp] = qb.z; pooled[3][2 * cp + 1] = qb.w;
    }

    // softmax + subtract + swish + channel max. swish monotone for z>-1.2785;
    // z = softmax - sub >= -max|sub| ~ -0.3 => max_co swish(z) = swish(max_co z).
    float4 resq;
    float* resf = (float*)&resq;
#pragma unroll
    for (int v = 0; v < 4; ++v) {
        float m = pooled[v][0];
#pragma unroll
        for (int co = 1; co < COUT; ++co) m = fmaxf(m, pooled[v][co]);
        float e[COUT];
        float s = 0.0f;
#pragma unroll
        for (int co = 0; co < COUT; ++co) {
            e[co] = __expf(pooled[v][co] - m);
            s += e[co];
        }
        const float inv = __builtin_amdgcn_rcpf(s);
        float zmax = -3.402823466e+38f;
#pragma unroll
        for (int co = 0; co < COUT; ++co)
            zmax = fmaxf(zmax, fmaf(e[co], inv, -sub[co]));
        resf[v] = zmax * __builtin_amdgcn_rcpf(1.0f + __expf(-zmax));
    }

    float* op = out + (((size_t)n * DHW + d) * DHW + h) * DHW + w0;
    *(float4*)op = resq;                             // coalesced 16B store
}

extern "C" void kernel_launch(void* const* d_in, const int* in_sizes, int n_in,
                              void* d_out, int out_size, void* d_ws, size_t ws_size,
                              hipStream_t stream) {
    const float* x   = (const float*)d_in[0];
    const float* w   = (const float*)d_in[1];
    const float* b   = (const float*)d_in[2];
    const float* sub = (const float*)d_in[3];
    float* out = (float*)d_out;

    dim3 block(16, 8, 1);                 // 16 w-quads x 8 h-rows = 128 threads
    dim3 grid(DHW / 8, DHW, 4);           // (h-groups, d, n) = 2048 blocks
    fused_convt_pool_softmax_swish_max<<<grid, block, 0, stream>>>(x, w, b, sub, out);
}